// Round 7
// baseline (258.148 us; speedup 1.0000x reference)
//
#include <hip/hip_runtime.h>

using short8  = __attribute__((ext_vector_type(8))) short;
using short4v = __attribute__((ext_vector_type(4))) short;
using floatx4 = __attribute__((ext_vector_type(4))) float;

#define MFMA_B16(a, b, c) __builtin_amdgcn_mfma_f32_16x16x32_bf16(a, b, c, 0, 0, 0)

__device__ __forceinline__ short f2bf(float f) {
  union { float f; unsigned u; } v; v.f = f;
  unsigned r = v.u + 0x7fffu + ((v.u >> 16) & 1u);
  return (short)(r >> 16);
}
// truncating cast (P>=0; bias cancels between PV numerator and ones-column denom)
__device__ __forceinline__ short f2bf_rtz(float f) {
  union { float f; unsigned u; } v; v.f = f;
  return (short)(v.u >> 16);
}

// async global->LDS, 16B per lane; lds dest = wave-uniform base + lane*16
__device__ __forceinline__ void gload_lds16(const short* g, short* l) {
  __builtin_amdgcn_global_load_lds(
      (const __attribute__((address_space(1))) unsigned int*)g,
      (__attribute__((address_space(3))) unsigned int*)l, 16, 0, 0);
}

// ---------------- prep: cast x -> bf16  +  transpose/cast weights ----------------
__global__ __launch_bounds__(256) void prep(
    const float4* __restrict__ x, short4v* __restrict__ xb,
    const float* __restrict__ w0, const float* __restrict__ w1,
    const float* __restrict__ w2, const float* __restrict__ w3,
    short* __restrict__ wT) {
  __shared__ float tile[32][33];
  int blk = blockIdx.x;
  if (blk < 8192) {
    int i = blk * 256 + threadIdx.x;
    float4 v = x[i];
    short4v o = { f2bf(v.x), f2bf(v.y), f2bf(v.z), f2bf(v.w) };
    xb[i] = o;
  } else {
    int r = blk - 8192;
    int z = r >> 10; r &= 1023;
    const float* w = z == 0 ? w0 : (z == 1 ? w1 : (z == 2 ? w2 : w3));
    short* out = wT + (size_t)z * 1024 * 1024;
    int n0 = (r & 31) * 32, k0 = (r >> 5) * 32;
    int tx = threadIdx.x & 31, ty = threadIdx.x >> 5;
#pragma unroll
    for (int i = 0; i < 4; ++i)
      tile[ty + i * 8][tx] = w[(size_t)(k0 + ty + i * 8) * 1024 + n0 + tx];
    __syncthreads();
#pragma unroll
    for (int i = 0; i < 4; ++i)
      out[(size_t)(n0 + ty + i * 8) * 1024 + k0 + tx] = f2bf(tile[tx][ty + i * 8]);
  }
}

// ---------------- QKV projection GEMM (fused, uniform epilogue) ----------------
// z=0: Q scaled by log2(e)/8 -> qkv slot 0; z=1: K -> slot 1;
// z=2: V -> vstage (attnb region; transposed into slot 2 by transpose_v).
__global__ __launch_bounds__(256) void gemm_qkv(
    const short* __restrict__ xb, const short* __restrict__ wT,
    const float* __restrict__ bq, const float* __restrict__ bk,
    const float* __restrict__ bv, short* __restrict__ qkv,
    short* __restrict__ vstage) {
  const int K = 1024;
  int z = blockIdx.z;
  const short* wt = wT + (size_t)z * 1024 * 1024;
  const float* bias = z == 0 ? bq : (z == 1 ? bk : bv);
  short* out = (z == 2) ? vstage : qkv + (size_t)z * 8192 * 1024;

  int m0 = blockIdx.x * 128, n0 = blockIdx.y * 128;
  __shared__ __align__(16) short a[128][32];
  __shared__ __align__(16) short bt[128][32];
  int tid = threadIdx.x;
  int w = tid >> 6, lane = tid & 63, quad = lane >> 4, l16 = lane & 15;
  int wm = (w >> 1) * 64, wn = (w & 1) * 64;
  floatx4 zf = {0.f, 0.f, 0.f, 0.f};
  floatx4 acc[4][4];
#pragma unroll
  for (int i = 0; i < 4; ++i)
#pragma unroll
    for (int j = 0; j < 4; ++j) acc[i][j] = zf;

  int rowL = lane >> 2;
  int segL = (lane & 3) * 8;
  const short* ga = xb + (size_t)(m0 + w * 32 + rowL) * K + segL;
  const short* gb = wt + (size_t)(n0 + w * 32 + rowL) * K + segL;
  short* la = &a[w * 32][0];
  short* lb = &bt[w * 32][0];

  for (int k0 = 0; k0 < K; k0 += 32) {
    __syncthreads();
    gload_lds16(ga + k0, la);
    gload_lds16(ga + (size_t)16 * K + k0, la + 16 * 32);
    gload_lds16(gb + k0, lb);
    gload_lds16(gb + (size_t)16 * K + k0, lb + 16 * 32);
    __syncthreads();
    short8 af[4], bf[4];
#pragma unroll
    for (int t = 0; t < 4; ++t) {
      af[t] = *(const short8*)(&a[wm + t * 16 + l16][quad * 8]);
      bf[t] = *(const short8*)(&bt[wn + t * 16 + l16][quad * 8]);
    }
#pragma unroll
    for (int i = 0; i < 4; ++i)
#pragma unroll
      for (int j = 0; j < 4; ++j)
        acc[i][j] = MFMA_B16(af[i], bf[j], acc[i][j]);
  }

  // Q pre-scaled by log2(e)/sqrt(D) so attention can use exp2
  float qs = (z == 0) ? 0.125f * 1.44269504f : 1.0f;
#pragma unroll
  for (int i = 0; i < 4; ++i)
#pragma unroll
    for (int j = 0; j < 4; ++j)
#pragma unroll
      for (int rg = 0; rg < 4; ++rg) {
        int m = m0 + wm + i * 16 + quad * 4 + rg;
        int cc = n0 + wn + j * 16 + l16;
        float v = (acc[i][j][rg] + bias[cc]) * qs;
        int b = m >> 12, l = m & 4095;
        int hh = cc >> 6, d = cc & 63;
        out[((size_t)(b * 16 + hh) * 4096 + l) * 64 + d] = f2bf(v);
      }
}

// ---------------- V transpose: (B,H,L,D) vstage -> (B,H,D,L) qkv slot 2 ----------------
__global__ __launch_bounds__(256) void transpose_v(const short* __restrict__ vin,
                                                   short* __restrict__ vout) {
  __shared__ __align__(16) short t[64][72];
  int bh = blockIdx.x >> 6;            // 0..31 (b*16+h)
  int l0 = (blockIdx.x & 63) * 64;     // L tile base
  const short* src = vin + ((size_t)bh * 4096 + l0) * 64;
  int tid = threadIdx.x;
  int row = tid >> 2, seg = (tid & 3) * 16;
  *(short8*)(&t[row][seg])     = *(const short8*)(src + row * 64 + seg);
  *(short8*)(&t[row][seg + 8]) = *(const short8*)(src + row * 64 + seg + 8);
  __syncthreads();
  short* dst = vout + (size_t)bh * 64 * 4096 + l0;
  short8 p0, p1;
#pragma unroll
  for (int j = 0; j < 8; ++j) { p0[j] = t[seg + j][row]; p1[j] = t[seg + 8 + j][row]; }
  *(short8*)(dst + (size_t)row * 4096 + seg)     = p0;
  *(short8*)(dst + (size_t)row * 4096 + seg + 8) = p1;
}

// ---------------- windowed attention ----------------
// K/V MFMA B-fragments loaded DIRECTLY from global (no LDS staging):
//   QK frag = K[key][dseg]  (16B contiguous in (B,H,L,D))
//   PV frag = Vt[d][keyseg] (16B contiguous in (B,H,D,L))
// LDS holds only the P matrix (C-layout -> A-layout transform).
// Out-of-range chunks: S stays 0 (skip loads/MFMA) -> P=1; V-frags zeroed.
__global__ __launch_bounds__(256) void attn_kern(const short* __restrict__ qkv,
                                                 short* __restrict__ attnb) {
  const int L = 4096, H = 16;
  int n = blockIdx.x, h = blockIdx.y, b = blockIdx.z;
  const size_t hs = (size_t)L * 64;
  const short* Qp = qkv + (size_t)(b * H + h) * hs;
  const short* Kp = qkv + (size_t)8192 * 1024 + (size_t)(b * H + h) * hs;
  const short* Vt = qkv + (size_t)2 * 8192 * 1024 + (size_t)(b * H + h) * hs; // (D,L)

  __shared__ __align__(16) short pl[4][32][136];

  int tid = threadIdx.x, w = tid >> 6, lane = tid & 63, quad = lane >> 4, l16 = lane & 15;

  short8 z8 = {0, 0, 0, 0, 0, 0, 0, 0};
  // ones B-fragment (col 0 of a 16-col tile = 1): sums P rows via MFMA
  short8 onesf;
  {
    short ov = (l16 == 0) ? (short)0x3F80 : (short)0;
#pragma unroll
    for (int j = 0; j < 8; ++j) onesf[j] = ov;
  }

  // preload Q A-fragments (Q pre-scaled by log2e/8)
  short8 qf[2][2];
#pragma unroll
  for (int rt = 0; rt < 2; ++rt)
#pragma unroll
    for (int ks = 0; ks < 2; ++ks)
      qf[rt][ks] = *(const short8*)(Qp + (size_t)(n * 128 + w * 32 + rt * 16 + l16) * 64 + ks * 32 + quad * 8);

  floatx4 zf = {0.f, 0.f, 0.f, 0.f};
  floatx4 o[2][4];
  floatx4 osum[2];
#pragma unroll
  for (int i = 0; i < 2; ++i) {
    osum[i] = zf;
#pragma unroll
    for (int j = 0; j < 4; ++j) o[i][j] = zf;
  }

#pragma unroll
  for (int c = 0; c < 3; ++c) {
    int bk = n - 1 + c;
    bool inr = (c == 1) || (c == 0 ? (n > 0) : (n < 31));

    // S = Q K^T; B-frags straight from global; skip fully-masked tiles
    floatx4 s[2][8];
#pragma unroll
    for (int rt = 0; rt < 2; ++rt)
#pragma unroll
      for (int ct = 0; ct < 8; ++ct) s[rt][ct] = zf;
    if (inr) {
      const short* kc_ = Kp + (size_t)bk * 128 * 64;
#pragma unroll
      for (int ct = 0; ct < 8; ++ct) {
        bool any = (c == 0) ? (ct >= w * 2) : (c == 2) ? (ct <= w * 2 + 1) : true;
        if (any) {
          const short* kr_ = kc_ + (ct * 16 + l16) * 64 + quad * 8;
          short8 kf0 = *(const short8*)(kr_);
          short8 kf1 = *(const short8*)(kr_ + 32);
#pragma unroll
          for (int rt = 0; rt < 2; ++rt) {
            bool valid = (c == 0) ? (ct >= w * 2 + rt) : (c == 2) ? (ct <= w * 2 + rt) : true;
            if (valid) {
              s[rt][ct] = MFMA_B16(qf[rt][0], kf0, s[rt][ct]);
              s[rt][ct] = MFMA_B16(qf[rt][1], kf1, s[rt][ct]);
            }
          }
        }
      }
    }

    if (c > 0) __syncthreads();   // prior chunk's P-readers done before overwrite

    // P = exp2(S) with band mask; skip dead tiles; zero-fill only when the
    // enclosing 32-key ks-tile is still live for this rt.
#pragma unroll
    for (int rt = 0; rt < 2; ++rt) {
      int wrt = w * 2 + rt;
#pragma unroll
      for (int ct = 0; ct < 8; ++ct) {
        bool tileMasked = (c == 0) ? (ct < wrt) : (c == 2) ? (ct > wrt) : false;
        bool ksDead = (c == 0) ? (2 * (ct >> 1) + 1 < wrt)
                    : (c == 2) ? (2 * (ct >> 1) > wrt) : false;
        if (ksDead) continue;
        if (tileMasked) {
#pragma unroll
          for (int rg = 0; rg < 4; ++rg)
            pl[w][rt * 16 + quad * 4 + rg][ct * 16 + l16] = 0;
        } else {
#pragma unroll
          for (int rg = 0; rg < 4; ++rg) {
            int r = w * 32 + rt * 16 + quad * 4 + rg;
            int j = ct * 16 + l16;
            float p = exp2f(s[rt][ct][rg]);
            if (c == 0) p = (j < r) ? 0.f : p;
            if (c == 2) p = (j > r) ? 0.f : p;
            pl[w][rt * 16 + quad * 4 + rg][ct * 16 + l16] = f2bf_rtz(p);
          }
        }
      }
    }

    __syncthreads();   // order P-stores before cross-lane P-loads

    // O += P V ; V B-frags straight from global (zero outside range)
    const short* vc_ = Vt + (size_t)bk * 128;
#pragma unroll
    for (int ks = 0; ks < 4; ++ks) {
      bool anyrt = (c == 0) ? (2 * ks + 1 >= w * 2) : (c == 2) ? (2 * ks <= w * 2 + 1) : true;
      if (!anyrt) continue;
      short8 vf[4];
#pragma unroll
      for (int ct = 0; ct < 4; ++ct)
        vf[ct] = inr ? *(const short8*)(vc_ + (size_t)(ct * 16 + l16) * 4096 + ks * 32 + quad * 8)
                     : z8;
#pragma unroll
      for (int rt = 0; rt < 2; ++rt) {
        int wrt = w * 2 + rt;
        bool ksDead = (c == 0) ? (2 * ks + 1 < wrt) : (c == 2) ? (2 * ks > wrt) : false;
        if (ksDead) continue;
        short8 pf = *(const short8*)(&pl[w][rt * 16 + l16][ks * 32 + quad * 8]);
#pragma unroll
        for (int ct = 0; ct < 4; ++ct) o[rt][ct] = MFMA_B16(pf, vf[ct], o[rt][ct]);
        osum[rt] = MFMA_B16(pf, onesf, osum[rt]);
      }
    }
  }

  // normalize + store to (B, L, C) bf16; sum lives in col 0 of the ones tile
#pragma unroll
  for (int rt = 0; rt < 2; ++rt) {
#pragma unroll
    for (int rg = 0; rg < 4; ++rg) {
      float ssum = __shfl(osum[rt][rg], lane & 48);
      float inv = 1.f / ssum;
      int r = n * 128 + w * 32 + rt * 16 + quad * 4 + rg;
#pragma unroll
      for (int ct = 0; ct < 4; ++ct)
        attnb[(size_t)(b * L + r) * 1024 + h * 64 + ct * 16 + l16] =
            f2bf(o[rt][ct][rg] * inv);
    }
  }
}

// ---------------- output projection GEMM (fp32 out), 64x128 tile ----------------
__global__ __launch_bounds__(256) void gemm_out(
    const short* __restrict__ attnb, const short* __restrict__ wTo,
    const float* __restrict__ bo, float* __restrict__ outp) {
  const int K = 1024;
  int m0 = blockIdx.x * 64, n0 = blockIdx.y * 128;
  __shared__ __align__(16) short a[64][32];
  __shared__ __align__(16) short bt[128][32];
  int tid = threadIdx.x;
  int w = tid >> 6, lane = tid & 63, quad = lane >> 4, l16 = lane & 15;
  int wm = (w >> 1) * 32, wn = (w & 1) * 64;
  floatx4 zf = {0.f, 0.f, 0.f, 0.f};
  floatx4 acc[2][4];
#pragma unroll
  for (int i = 0; i < 2; ++i)
#pragma unroll
    for (int j = 0; j < 4; ++j) acc[i][j] = zf;

  int rowL = lane >> 2;
  int segL = (lane & 3) * 8;
  // wave w stages A rows [w*16, w*16+16) and B rows [w*32, w*32+32)
  const short* ga = attnb + (size_t)(m0 + w * 16 + rowL) * K + segL;
  const short* gb = wTo + (size_t)(n0 + w * 32 + rowL) * K + segL;
  short* la = &a[w * 16][0];
  short* lb = &bt[w * 32][0];

  for (int k0 = 0; k0 < K; k0 += 32) {
    __syncthreads();
    gload_lds16(ga + k0, la);
    gload_lds16(gb + k0, lb);
    gload_lds16(gb + (size_t)16 * K + k0, lb + 16 * 32);
    __syncthreads();
    short8 af[2], bf[4];
#pragma unroll
    for (int t = 0; t < 2; ++t)
      af[t] = *(const short8*)(&a[wm + t * 16 + l16][quad * 8]);
#pragma unroll
    for (int t = 0; t < 4; ++t)
      bf[t] = *(const short8*)(&bt[wn + t * 16 + l16][quad * 8]);
#pragma unroll
    for (int i = 0; i < 2; ++i)
#pragma unroll
      for (int j = 0; j < 4; ++j)
        acc[i][j] = MFMA_B16(af[i], bf[j], acc[i][j]);
  }
#pragma unroll
  for (int i = 0; i < 2; ++i)
#pragma unroll
    for (int j = 0; j < 4; ++j)
#pragma unroll
      for (int rg = 0; rg < 4; ++rg) {
        int m = m0 + wm + i * 16 + quad * 4 + rg;
        int c = n0 + wn + j * 16 + l16;
        outp[(size_t)m * 1024 + c] = acc[i][j][rg] + bo[c];
      }
}

extern "C" void kernel_launch(void* const* d_in, const int* in_sizes, int n_in,
                              void* d_out, int out_size, void* d_ws, size_t ws_size,
                              hipStream_t stream) {
  const float* x  = (const float*)d_in[0];
  const float* wq = (const float*)d_in[1];
  const float* bq = (const float*)d_in[2];
  const float* wk = (const float*)d_in[3];
  const float* bk = (const float*)d_in[4];
  const float* wv = (const float*)d_in[5];
  const float* bv = (const float*)d_in[6];
  const float* wo = (const float*)d_in[7];
  const float* bo = (const float*)d_in[8];

  char* ws = (char*)d_ws;
  short* xb     = (short*)ws;                   // [0,16M): x bf16
  short* wT     = (short*)(ws + (16u << 20));   // [16M,24M): 4x W^T bf16
  short* qkv    = (short*)(ws + (24u << 20));   // [24M,72M): Q,K (B,H,L,D) + V^T (B,H,D,L)
  short* attnb  = (short*)(ws + (72u << 20));   // [72M,88M): V stage, then attention out
  short* vstage = attnb;                        // V (B,H,L,D), consumed by transpose_v before attn writes

  prep<<<12288, 256, 0, stream>>>((const float4*)x, (short4v*)xb, wq, wk, wv, wo, wT);
  gemm_qkv<<<dim3(64, 8, 3), 256, 0, stream>>>(xb, wT, bq, bk, bv, qkv, vstage);
  transpose_v<<<2048, 256, 0, stream>>>(vstage, qkv + (size_t)2 * 8192 * 1024);
  attn_kern<<<dim3(32, 16, 2), 256, 0, stream>>>(qkv, attnb);
  gemm_out<<<dim3(128, 8), 256, 0, stream>>>(attnb, wT + 3u * 1024 * 1024, bo, (float*)d_out);
}

// Round 8
// 242.190 us; speedup vs baseline: 1.0659x; 1.0659x over previous
//
#include <hip/hip_runtime.h>

using short8  = __attribute__((ext_vector_type(8))) short;
using short4v = __attribute__((ext_vector_type(4))) short;
using floatx4 = __attribute__((ext_vector_type(4))) float;

#define MFMA_B16(a, b, c) __builtin_amdgcn_mfma_f32_16x16x32_bf16(a, b, c, 0, 0, 0)

__device__ __forceinline__ short f2bf(float f) {
  union { float f; unsigned u; } v; v.f = f;
  unsigned r = v.u + 0x7fffu + ((v.u >> 16) & 1u);
  return (short)(r >> 16);
}
// truncating cast (P>=0; bias cancels between PV numerator and ones-column denom)
__device__ __forceinline__ short f2bf_rtz(float f) {
  union { float f; unsigned u; } v; v.f = f;
  return (short)(v.u >> 16);
}

// async global->LDS, 16B per lane; lds dest = wave-uniform base + lane*16
__device__ __forceinline__ void gload_lds16(const short* g, short* l) {
  __builtin_amdgcn_global_load_lds(
      (const __attribute__((address_space(1))) unsigned int*)g,
      (__attribute__((address_space(3))) unsigned int*)l, 16, 0, 0);
}

// ---------------- prep: cast x -> bf16  +  transpose/cast weights ----------------
__global__ __launch_bounds__(256) void prep(
    const float4* __restrict__ x, short4v* __restrict__ xb,
    const float* __restrict__ w0, const float* __restrict__ w1,
    const float* __restrict__ w2, const float* __restrict__ w3,
    short* __restrict__ wT) {
  __shared__ float tile[32][33];
  int blk = blockIdx.x;
  if (blk < 8192) {
    int i = blk * 256 + threadIdx.x;
    float4 v = x[i];
    short4v o = { f2bf(v.x), f2bf(v.y), f2bf(v.z), f2bf(v.w) };
    xb[i] = o;
  } else {
    int r = blk - 8192;
    int z = r >> 10; r &= 1023;
    const float* w = z == 0 ? w0 : (z == 1 ? w1 : (z == 2 ? w2 : w3));
    short* out = wT + (size_t)z * 1024 * 1024;
    int n0 = (r & 31) * 32, k0 = (r >> 5) * 32;
    int tx = threadIdx.x & 31, ty = threadIdx.x >> 5;
#pragma unroll
    for (int i = 0; i < 4; ++i)
      tile[ty + i * 8][tx] = w[(size_t)(k0 + ty + i * 8) * 1024 + n0 + tx];
    __syncthreads();
#pragma unroll
    for (int i = 0; i < 4; ++i)
      out[(size_t)(n0 + ty + i * 8) * 1024 + k0 + tx] = f2bf(tile[tx][ty + i * 8]);
  }
}

// ---------------- QKV projection GEMM (fused, uniform epilogue, BK=64) ----------------
// z=0: Q scaled by log2(e)/8; z=1: K; z=2: V.  All out (B,H,L,D) bf16.
__global__ __launch_bounds__(256) void gemm_qkv(
    const short* __restrict__ xb, const short* __restrict__ wT,
    const float* __restrict__ bq, const float* __restrict__ bk,
    const float* __restrict__ bv, short* __restrict__ qkv) {
  const int K = 1024;
  int z = blockIdx.z;
  const short* wt = wT + (size_t)z * 1024 * 1024;
  const float* bias = z == 0 ? bq : (z == 1 ? bk : bv);
  short* out = qkv + (size_t)z * 8192 * 1024;

  int m0 = blockIdx.x * 128, n0 = blockIdx.y * 128;
  __shared__ __align__(16) short a[128][64];   // BK=64, unpadded (global_load_lds)
  __shared__ __align__(16) short bt[128][64];
  int tid = threadIdx.x;
  int w = tid >> 6, lane = tid & 63, quad = lane >> 4, l16 = lane & 15;
  int wm = (w >> 1) * 64, wn = (w & 1) * 64;
  floatx4 zf = {0.f, 0.f, 0.f, 0.f};
  floatx4 acc[4][4];
#pragma unroll
  for (int i = 0; i < 4; ++i)
#pragma unroll
    for (int j = 0; j < 4; ++j) acc[i][j] = zf;

  // one gload_lds16 call covers 8 rows of 64 shorts (lane -> row lane>>3, seg (lane&7)*8)
  int rowL = lane >> 3;          // 0..7
  int segL = (lane & 7) * 8;     // short offset within row
  const short* ga = xb + (size_t)(m0 + w * 32 + rowL) * K + segL;
  const short* gb = wt + (size_t)(n0 + w * 32 + rowL) * K + segL;
  short* la = &a[w * 32][0];
  short* lb = &bt[w * 32][0];

  for (int k0 = 0; k0 < K; k0 += 64) {
    __syncthreads();
#pragma unroll
    for (int cc = 0; cc < 4; ++cc) {
      gload_lds16(ga + (size_t)(cc * 8) * K + k0, la + cc * 8 * 64);
      gload_lds16(gb + (size_t)(cc * 8) * K + k0, lb + cc * 8 * 64);
    }
    __syncthreads();
#pragma unroll
    for (int kk = 0; kk < 2; ++kk) {
      short8 af[4], bf[4];
#pragma unroll
      for (int t = 0; t < 4; ++t) {
        af[t] = *(const short8*)(&a[wm + t * 16 + l16][kk * 32 + quad * 8]);
        bf[t] = *(const short8*)(&bt[wn + t * 16 + l16][kk * 32 + quad * 8]);
      }
#pragma unroll
      for (int i = 0; i < 4; ++i)
#pragma unroll
        for (int j = 0; j < 4; ++j)
          acc[i][j] = MFMA_B16(af[i], bf[j], acc[i][j]);
    }
  }

  // Q pre-scaled by log2(e)/sqrt(D) so attention can use exp2
  float qs = (z == 0) ? 0.125f * 1.44269504f : 1.0f;
#pragma unroll
  for (int i = 0; i < 4; ++i)
#pragma unroll
    for (int j = 0; j < 4; ++j)
#pragma unroll
      for (int rg = 0; rg < 4; ++rg) {
        int m = m0 + wm + i * 16 + quad * 4 + rg;
        int cc = n0 + wn + j * 16 + l16;
        float v = (acc[i][j][rg] + bias[cc]) * qs;
        int b = m >> 12, l = m & 4095;
        int hh = cc >> 6, d = cc & 63;
        out[((size_t)(b * 16 + hh) * 4096 + l) * 64 + d] = f2bf(v);
      }
}

// ---------------- windowed attention ----------------
// K staged to LDS vectorized; V staged TRANSPOSED in LDS from (B,H,L,D)
// via scalar writes with a 2-way-bank-aliased mapping (free per m136).
// No max-subtraction softmax; row sums via register ones-fragment MFMA.
// Wave-uniform skipping of fully-masked 16-col tiles in the corner chunks.
__global__ __launch_bounds__(256) void attn_kern(const short* __restrict__ qkv,
                                                 short* __restrict__ attnb) {
  const int L = 4096, H = 16;
  int n = blockIdx.x, h = blockIdx.y, b = blockIdx.z;
  const size_t hs = (size_t)L * 64;
  const short* Qp = qkv + (size_t)(b * H + h) * hs;
  const short* Kp = qkv + (size_t)8192 * 1024 + (size_t)(b * H + h) * hs;
  const short* Vp = qkv + (size_t)2 * 8192 * 1024 + (size_t)(b * H + h) * hs;

  __shared__ __align__(16) short kt[128][72];
  __shared__ __align__(16) short vt[64][136];   // vt[d][key]
  __shared__ __align__(16) short pl[4][32][136];

  int tid = threadIdx.x, w = tid >> 6, lane = tid & 63, quad = lane >> 4, l16 = lane & 15;

  // ones B-fragment (col 0 of a 16-col tile = 1): sums P rows via MFMA
  short8 onesf;
  {
    short ov = (l16 == 0) ? (short)0x3F80 : (short)0;
#pragma unroll
    for (int j = 0; j < 8; ++j) onesf[j] = ov;
  }

  // preload Q A-fragments (Q pre-scaled by log2e/8)
  short8 qf[2][2];
#pragma unroll
  for (int rt = 0; rt < 2; ++rt)
#pragma unroll
    for (int ks = 0; ks < 2; ++ks)
      qf[rt][ks] = *(const short8*)(Qp + (size_t)(n * 128 + w * 32 + rt * 16 + l16) * 64 + ks * 32 + quad * 8);

  floatx4 zf = {0.f, 0.f, 0.f, 0.f};
  floatx4 o[2][4];
  floatx4 osum[2];
#pragma unroll
  for (int i = 0; i < 2; ++i) {
    osum[i] = zf;
#pragma unroll
    for (int j = 0; j < 4; ++j) o[i][j] = zf;
  }

#pragma unroll
  for (int c = 0; c < 3; ++c) {
    int bk = n - 1 + c;
    bool inr = (c == 1) || (c == 0 ? (n > 0) : (n < 31));
    __syncthreads();   // prior chunk's kt/vt readers done before restage
    if (inr) {
      const short* kc_ = Kp + (size_t)bk * 128 * 64;
      int kr = tid >> 2, ksg = (tid & 3) * 16;
#pragma unroll
      for (int p = 0; p < 2; ++p) {
        int r2 = p * 64 + kr;
        *(short8*)(&kt[r2][ksg])     = *(const short8*)(kc_ + r2 * 64 + ksg);
        *(short8*)(&kt[r2][ksg + 8]) = *(const short8*)(kc_ + r2 * 64 + ksg + 8);
      }
      // V transpose-in-LDS: thread -> key (tid&31), d-seg (tid>>5)*8
      const short* vc_ = Vp + (size_t)bk * 128 * 64;
      int vkey = tid & 31, vsg = (tid >> 5) * 8;
#pragma unroll
      for (int p = 0; p < 4; ++p) {
        int r2 = p * 32 + vkey;
        short8 vv = *(const short8*)(vc_ + r2 * 64 + vsg);
#pragma unroll
        for (int j = 0; j < 8; ++j) vt[vsg + j][r2] = vv[j];
      }
    } else {
      short8 z8 = {0, 0, 0, 0, 0, 0, 0, 0};
      int kr = tid >> 2, ksg = (tid & 3) * 16;
#pragma unroll
      for (int p = 0; p < 2; ++p) {
        int r2 = p * 64 + kr;
        *(short8*)(&kt[r2][ksg])     = z8;
        *(short8*)(&kt[r2][ksg + 8]) = z8;
      }
      int vr = tid >> 2, vsg2 = (tid & 3) * 32;
#pragma unroll
      for (int q2 = 0; q2 < 4; ++q2) *(short8*)(&vt[vr][vsg2 + q2 * 8]) = z8;
    }
    __syncthreads();

    // S = Q K^T; skip fully-masked 16-col tiles (wave-uniform: wrt = w*2+rt)
    floatx4 s[2][8];
#pragma unroll
    for (int rt = 0; rt < 2; ++rt)
#pragma unroll
      for (int ct = 0; ct < 8; ++ct) s[rt][ct] = zf;
#pragma unroll
    for (int ct = 0; ct < 8; ++ct) {
      bool any = (c == 0) ? (ct >= w * 2) : (c == 2) ? (ct <= w * 2 + 1) : true;
      if (any) {
        short8 kf0 = *(const short8*)(&kt[ct * 16 + l16][quad * 8]);
        short8 kf1 = *(const short8*)(&kt[ct * 16 + l16][32 + quad * 8]);
#pragma unroll
        for (int rt = 0; rt < 2; ++rt) {
          bool valid = (c == 0) ? (ct >= w * 2 + rt) : (c == 2) ? (ct <= w * 2 + rt) : true;
          if (valid) {
            s[rt][ct] = MFMA_B16(qf[rt][0], kf0, s[rt][ct]);
            s[rt][ct] = MFMA_B16(qf[rt][1], kf1, s[rt][ct]);
          }
        }
      }
    }

    // P = exp2(S) with band mask; skip dead tiles; zero-fill only when the
    // enclosing 32-key ks-tile is still live for this rt.
#pragma unroll
    for (int rt = 0; rt < 2; ++rt) {
      int wrt = w * 2 + rt;
#pragma unroll
      for (int ct = 0; ct < 8; ++ct) {
        bool tileMasked = (c == 0) ? (ct < wrt) : (c == 2) ? (ct > wrt) : false;
        bool ksDead = (c == 0) ? (2 * (ct >> 1) + 1 < wrt)
                    : (c == 2) ? (2 * (ct >> 1) > wrt) : false;
        if (ksDead) continue;
        if (tileMasked) {
#pragma unroll
          for (int rg = 0; rg < 4; ++rg)
            pl[w][rt * 16 + quad * 4 + rg][ct * 16 + l16] = 0;
        } else {
#pragma unroll
          for (int rg = 0; rg < 4; ++rg) {
            int r = w * 32 + rt * 16 + quad * 4 + rg;
            int j = ct * 16 + l16;
            float p = exp2f(s[rt][ct][rg]);
            if (c == 0) p = (j < r) ? 0.f : p;
            if (c == 2) p = (j > r) ? 0.f : p;
            pl[w][rt * 16 + quad * 4 + rg][ct * 16 + l16] = f2bf_rtz(p);
          }
        }
      }
    }

    __syncthreads();   // order P-stores before cross-lane P-loads

    // O += P V ; row sums via ones-fragment; skip dead ks-tiles
#pragma unroll
    for (int ks = 0; ks < 4; ++ks) {
      bool anyrt = (c == 0) ? (2 * ks + 1 >= w * 2) : (c == 2) ? (2 * ks <= w * 2 + 1) : true;
      if (!anyrt) continue;
      short8 vf[4];
#pragma unroll
      for (int ct = 0; ct < 4; ++ct)
        vf[ct] = *(const short8*)(&vt[ct * 16 + l16][ks * 32 + quad * 8]);
#pragma unroll
      for (int rt = 0; rt < 2; ++rt) {
        int wrt = w * 2 + rt;
        bool ksDead = (c == 0) ? (2 * ks + 1 < wrt) : (c == 2) ? (2 * ks > wrt) : false;
        if (ksDead) continue;
        short8 pf = *(const short8*)(&pl[w][rt * 16 + l16][ks * 32 + quad * 8]);
#pragma unroll
        for (int ct = 0; ct < 4; ++ct) o[rt][ct] = MFMA_B16(pf, vf[ct], o[rt][ct]);
        osum[rt] = MFMA_B16(pf, onesf, osum[rt]);
      }
    }
  }

  // normalize + store to (B, L, C) bf16; sum lives in col 0 of the ones tile
#pragma unroll
  for (int rt = 0; rt < 2; ++rt) {
#pragma unroll
    for (int rg = 0; rg < 4; ++rg) {
      float ssum = __shfl(osum[rt][rg], lane & 48);
      float inv = 1.f / ssum;
      int r = n * 128 + w * 32 + rt * 16 + quad * 4 + rg;
#pragma unroll
      for (int ct = 0; ct < 4; ++ct)
        attnb[(size_t)(b * L + r) * 1024 + h * 64 + ct * 16 + l16] =
            f2bf(o[rt][ct][rg] * inv);
    }
  }
}

// ---------------- output projection GEMM (fp32 out), 128x128 ----------------
__global__ __launch_bounds__(256) void gemm_out(
    const short* __restrict__ attnb, const short* __restrict__ wTo,
    const float* __restrict__ bo, float* __restrict__ outp) {
  const int K = 1024;
  int m0 = blockIdx.x * 128, n0 = blockIdx.y * 128;
  __shared__ __align__(16) short a[128][32];
  __shared__ __align__(16) short bt[128][32];
  int tid = threadIdx.x;
  int w = tid >> 6, lane = tid & 63, quad = lane >> 4, l16 = lane & 15;
  int wm = (w >> 1) * 64, wn = (w & 1) * 64;
  floatx4 zf = {0.f, 0.f, 0.f, 0.f};
  floatx4 acc[4][4];
#pragma unroll
  for (int i = 0; i < 4; ++i)
#pragma unroll
    for (int j = 0; j < 4; ++j) acc[i][j] = zf;

  int rowL = lane >> 2;
  int segL = (lane & 3) * 8;
  const short* ga = attnb + (size_t)(m0 + w * 32 + rowL) * K + segL;
  const short* gb = wTo + (size_t)(n0 + w * 32 + rowL) * K + segL;
  short* la = &a[w * 32][0];
  short* lb = &bt[w * 32][0];

  for (int k0 = 0; k0 < K; k0 += 32) {
    __syncthreads();
    gload_lds16(ga + k0, la);
    gload_lds16(ga + (size_t)16 * K + k0, la + 16 * 32);
    gload_lds16(gb + k0, lb);
    gload_lds16(gb + (size_t)16 * K + k0, lb + 16 * 32);
    __syncthreads();
    short8 af[4], bf[4];
#pragma unroll
    for (int t = 0; t < 4; ++t) {
      af[t] = *(const short8*)(&a[wm + t * 16 + l16][quad * 8]);
      bf[t] = *(const short8*)(&bt[wn + t * 16 + l16][quad * 8]);
    }
#pragma unroll
    for (int i = 0; i < 4; ++i)
#pragma unroll
      for (int j = 0; j < 4; ++j)
        acc[i][j] = MFMA_B16(af[i], bf[j], acc[i][j]);
  }
#pragma unroll
  for (int i = 0; i < 4; ++i)
#pragma unroll
    for (int j = 0; j < 4; ++j)
#pragma unroll
      for (int rg = 0; rg < 4; ++rg) {
        int m = m0 + wm + i * 16 + quad * 4 + rg;
        int c = n0 + wn + j * 16 + l16;
        outp[(size_t)m * 1024 + c] = acc[i][j][rg] + bo[c];
      }
}

extern "C" void kernel_launch(void* const* d_in, const int* in_sizes, int n_in,
                              void* d_out, int out_size, void* d_ws, size_t ws_size,
                              hipStream_t stream) {
  const float* x  = (const float*)d_in[0];
  const float* wq = (const float*)d_in[1];
  const float* bq = (const float*)d_in[2];
  const float* wk = (const float*)d_in[3];
  const float* bk = (const float*)d_in[4];
  const float* wv = (const float*)d_in[5];
  const float* bv = (const float*)d_in[6];
  const float* wo = (const float*)d_in[7];
  const float* bo = (const float*)d_in[8];

  char* ws = (char*)d_ws;
  short* xb    = (short*)ws;                   // [0,16M): x bf16
  short* wT    = (short*)(ws + (16u << 20));   // [16M,24M): 4x W^T bf16
  short* qkv   = (short*)(ws + (24u << 20));   // [24M,72M): Q,K,V in (B,H,L,D)
  short* attnb = (short*)(ws + (72u << 20));   // [72M,88M): attention out (B,L,C) bf16

  prep<<<12288, 256, 0, stream>>>((const float4*)x, (short4v*)xb, wq, wk, wv, wo, wT);
  gemm_qkv<<<dim3(64, 8, 3), 256, 0, stream>>>(xb, wT, bq, bk, bv, qkv);
  attn_kern<<<dim3(32, 16, 2), 256, 0, stream>>>(qkv, attnb);
  gemm_out<<<dim3(64, 8), 256, 0, stream>>>(attnb, wT + 3u * 1024 * 1024, bo, (float*)d_out);
}

// Round 9
// 225.050 us; speedup vs baseline: 1.1471x; 1.0762x over previous
//
#include <hip/hip_runtime.h>

using short8  = __attribute__((ext_vector_type(8))) short;
using short4v = __attribute__((ext_vector_type(4))) short;
using floatx4 = __attribute__((ext_vector_type(4))) float;

#define MFMA_B16(a, b, c) __builtin_amdgcn_mfma_f32_16x16x32_bf16(a, b, c, 0, 0, 0)

__device__ __forceinline__ short f2bf(float f) {
  union { float f; unsigned u; } v; v.f = f;
  unsigned r = v.u + 0x7fffu + ((v.u >> 16) & 1u);
  return (short)(r >> 16);
}
// truncating cast (P>=0; bias cancels between PV numerator and ones-column denom)
__device__ __forceinline__ short f2bf_rtz(float f) {
  union { float f; unsigned u; } v; v.f = f;
  return (short)(v.u >> 16);
}

// async global->LDS, 16B per lane; lds dest = wave-uniform base + lane*16
__device__ __forceinline__ void gload_lds16(const short* g, short* l) {
  __builtin_amdgcn_global_load_lds(
      (const __attribute__((address_space(1))) unsigned int*)g,
      (__attribute__((address_space(3))) unsigned int*)l, 16, 0, 0);
}

// ---------------- prep: cast x -> bf16  +  transpose/cast weights ----------------
__global__ __launch_bounds__(256) void prep(
    const float4* __restrict__ x, short4v* __restrict__ xb,
    const float* __restrict__ w0, const float* __restrict__ w1,
    const float* __restrict__ w2, const float* __restrict__ w3,
    short* __restrict__ wT) {
  __shared__ float tile[32][33];
  int blk = blockIdx.x;
  if (blk < 8192) {
    int i = blk * 256 + threadIdx.x;
    float4 v = x[i];
    short4v o = { f2bf(v.x), f2bf(v.y), f2bf(v.z), f2bf(v.w) };
    xb[i] = o;
  } else {
    int r = blk - 8192;
    int z = r >> 10; r &= 1023;
    const float* w = z == 0 ? w0 : (z == 1 ? w1 : (z == 2 ? w2 : w3));
    short* out = wT + (size_t)z * 1024 * 1024;
    int n0 = (r & 31) * 32, k0 = (r >> 5) * 32;
    int tx = threadIdx.x & 31, ty = threadIdx.x >> 5;
#pragma unroll
    for (int i = 0; i < 4; ++i)
      tile[ty + i * 8][tx] = w[(size_t)(k0 + ty + i * 8) * 1024 + n0 + tx];
    __syncthreads();
#pragma unroll
    for (int i = 0; i < 4; ++i)
      out[(size_t)(n0 + ty + i * 8) * 1024 + k0 + tx] = f2bf(tile[tx][ty + i * 8]);
  }
}

// ---------------- QKV projection GEMM (fused, uniform epilogue, BK=32) ----------------
// z=0: Q scaled by log2(e)/8; z=1: K; z=2: V.  All out (B,H,L,D) bf16.
__global__ __launch_bounds__(256) void gemm_qkv(
    const short* __restrict__ xb, const short* __restrict__ wT,
    const float* __restrict__ bq, const float* __restrict__ bk,
    const float* __restrict__ bv, short* __restrict__ qkv) {
  const int K = 1024;
  int z = blockIdx.z;
  const short* wt = wT + (size_t)z * 1024 * 1024;
  const float* bias = z == 0 ? bq : (z == 1 ? bk : bv);
  short* out = qkv + (size_t)z * 8192 * 1024;

  int m0 = blockIdx.x * 128, n0 = blockIdx.y * 128;
  __shared__ __align__(16) short a[128][32];   // unpadded: global_load_lds layout
  __shared__ __align__(16) short bt[128][32];
  int tid = threadIdx.x;
  int w = tid >> 6, lane = tid & 63, quad = lane >> 4, l16 = lane & 15;
  int wm = (w >> 1) * 64, wn = (w & 1) * 64;
  floatx4 zf = {0.f, 0.f, 0.f, 0.f};
  floatx4 acc[4][4];
#pragma unroll
  for (int i = 0; i < 4; ++i)
#pragma unroll
    for (int j = 0; j < 4; ++j) acc[i][j] = zf;

  int rowL = lane >> 2;          // 0..15
  int segL = (lane & 3) * 8;     // short offset within row
  const short* ga = xb + (size_t)(m0 + w * 32 + rowL) * K + segL;
  const short* gb = wt + (size_t)(n0 + w * 32 + rowL) * K + segL;
  short* la = &a[w * 32][0];
  short* lb = &bt[w * 32][0];

  for (int k0 = 0; k0 < K; k0 += 32) {
    __syncthreads();
    gload_lds16(ga + k0, la);
    gload_lds16(ga + (size_t)16 * K + k0, la + 16 * 32);
    gload_lds16(gb + k0, lb);
    gload_lds16(gb + (size_t)16 * K + k0, lb + 16 * 32);
    __syncthreads();
    short8 af[4], bf[4];
#pragma unroll
    for (int t = 0; t < 4; ++t) {
      af[t] = *(const short8*)(&a[wm + t * 16 + l16][quad * 8]);
      bf[t] = *(const short8*)(&bt[wn + t * 16 + l16][quad * 8]);
    }
#pragma unroll
    for (int i = 0; i < 4; ++i)
#pragma unroll
      for (int j = 0; j < 4; ++j)
        acc[i][j] = MFMA_B16(af[i], bf[j], acc[i][j]);
  }

  // Q pre-scaled by log2(e)/sqrt(D) so attention can use exp2
  float qs = (z == 0) ? 0.125f * 1.44269504f : 1.0f;
#pragma unroll
  for (int i = 0; i < 4; ++i)
#pragma unroll
    for (int j = 0; j < 4; ++j)
#pragma unroll
      for (int rg = 0; rg < 4; ++rg) {
        int m = m0 + wm + i * 16 + quad * 4 + rg;
        int cc = n0 + wn + j * 16 + l16;
        float v = (acc[i][j][rg] + bias[cc]) * qs;
        int b = m >> 12, l = m & 4095;
        int hh = cc >> 6, d = cc & 63;
        out[((size_t)(b * 16 + hh) * 4096 + l) * 64 + d] = f2bf(v);
      }
}

// ---------------- windowed attention ----------------
// K staged to LDS vectorized; V staged TRANSPOSED in LDS from (B,H,L,D)
// via scalar writes with a 2-way-bank-aliased mapping (free per m136).
// No max-subtraction softmax; row sums via register ones-fragment MFMA.
// Wave-uniform skipping of fully-masked 16-col tiles; per-element band
// masking only on the diagonal tile (ct == wrt).
__global__ __launch_bounds__(256) void attn_kern(const short* __restrict__ qkv,
                                                 short* __restrict__ attnb) {
  const int L = 4096, H = 16;
  int n = blockIdx.x, h = blockIdx.y, b = blockIdx.z;
  const size_t hs = (size_t)L * 64;
  const short* Qp = qkv + (size_t)(b * H + h) * hs;
  const short* Kp = qkv + (size_t)8192 * 1024 + (size_t)(b * H + h) * hs;
  const short* Vp = qkv + (size_t)2 * 8192 * 1024 + (size_t)(b * H + h) * hs;

  __shared__ __align__(16) short kt[128][72];
  __shared__ __align__(16) short vt[64][136];   // vt[d][key]
  __shared__ __align__(16) short pl[4][32][136];

  int tid = threadIdx.x, w = tid >> 6, lane = tid & 63, quad = lane >> 4, l16 = lane & 15;

  // ones B-fragment (col 0 of a 16-col tile = 1): sums P rows via MFMA
  short8 onesf;
  {
    short ov = (l16 == 0) ? (short)0x3F80 : (short)0;
#pragma unroll
    for (int j = 0; j < 8; ++j) onesf[j] = ov;
  }

  // preload Q A-fragments (Q pre-scaled by log2e/8)
  short8 qf[2][2];
#pragma unroll
  for (int rt = 0; rt < 2; ++rt)
#pragma unroll
    for (int ks = 0; ks < 2; ++ks)
      qf[rt][ks] = *(const short8*)(Qp + (size_t)(n * 128 + w * 32 + rt * 16 + l16) * 64 + ks * 32 + quad * 8);

  floatx4 zf = {0.f, 0.f, 0.f, 0.f};
  floatx4 o[2][4];
  floatx4 osum[2];
#pragma unroll
  for (int i = 0; i < 2; ++i) {
    osum[i] = zf;
#pragma unroll
    for (int j = 0; j < 4; ++j) o[i][j] = zf;
  }

#pragma unroll
  for (int c = 0; c < 3; ++c) {
    int bk = n - 1 + c;
    bool inr = (c == 1) || (c == 0 ? (n > 0) : (n < 31));
    __syncthreads();   // prior chunk's kt/vt readers done before restage
    if (inr) {
      const short* kc_ = Kp + (size_t)bk * 128 * 64;
      int kr = tid >> 2, ksg = (tid & 3) * 16;
#pragma unroll
      for (int p = 0; p < 2; ++p) {
        int r2 = p * 64 + kr;
        *(short8*)(&kt[r2][ksg])     = *(const short8*)(kc_ + r2 * 64 + ksg);
        *(short8*)(&kt[r2][ksg + 8]) = *(const short8*)(kc_ + r2 * 64 + ksg + 8);
      }
      // V transpose-in-LDS: thread -> key (tid&31), d-seg (tid>>5)*8
      const short* vc_ = Vp + (size_t)bk * 128 * 64;
      int vkey = tid & 31, vsg = (tid >> 5) * 8;
#pragma unroll
      for (int p = 0; p < 4; ++p) {
        int r2 = p * 32 + vkey;
        short8 vv = *(const short8*)(vc_ + r2 * 64 + vsg);
#pragma unroll
        for (int j = 0; j < 8; ++j) vt[vsg + j][r2] = vv[j];
      }
    } else {
      short8 z8 = {0, 0, 0, 0, 0, 0, 0, 0};
      int kr = tid >> 2, ksg = (tid & 3) * 16;
#pragma unroll
      for (int p = 0; p < 2; ++p) {
        int r2 = p * 64 + kr;
        *(short8*)(&kt[r2][ksg])     = z8;
        *(short8*)(&kt[r2][ksg + 8]) = z8;
      }
      int vr = tid >> 2, vsg2 = (tid & 3) * 32;
#pragma unroll
      for (int q2 = 0; q2 < 4; ++q2) *(short8*)(&vt[vr][vsg2 + q2 * 8]) = z8;
    }
    __syncthreads();

    // S = Q K^T; skip fully-masked 16-col tiles (wave-uniform: wrt = w*2+rt)
    floatx4 s[2][8];
#pragma unroll
    for (int rt = 0; rt < 2; ++rt)
#pragma unroll
      for (int ct = 0; ct < 8; ++ct) s[rt][ct] = zf;
#pragma unroll
    for (int ct = 0; ct < 8; ++ct) {
      bool any = (c == 0) ? (ct >= w * 2) : (c == 2) ? (ct <= w * 2 + 1) : true;
      if (any) {
        short8 kf0 = *(const short8*)(&kt[ct * 16 + l16][quad * 8]);
        short8 kf1 = *(const short8*)(&kt[ct * 16 + l16][32 + quad * 8]);
#pragma unroll
        for (int rt = 0; rt < 2; ++rt) {
          bool valid = (c == 0) ? (ct >= w * 2 + rt) : (c == 2) ? (ct <= w * 2 + rt) : true;
          if (valid) {
            s[rt][ct] = MFMA_B16(qf[rt][0], kf0, s[rt][ct]);
            s[rt][ct] = MFMA_B16(qf[rt][1], kf1, s[rt][ct]);
          }
        }
      }
    }

    // P = exp2(S); per-element mask only on the diagonal tile; zero-fill
    // fully-masked tiles whose enclosing 32-key ks-tile is still live.
#pragma unroll
    for (int rt = 0; rt < 2; ++rt) {
      int wrt = w * 2 + rt;
#pragma unroll
      for (int ct = 0; ct < 8; ++ct) {
        bool tileMasked = (c == 0) ? (ct < wrt) : (c == 2) ? (ct > wrt) : false;
        bool ksDead = (c == 0) ? (2 * (ct >> 1) + 1 < wrt)
                    : (c == 2) ? (2 * (ct >> 1) > wrt) : false;
        bool diag = (c != 1) && (ct == wrt);
        if (ksDead) continue;
        if (tileMasked) {
#pragma unroll
          for (int rg = 0; rg < 4; ++rg)
            pl[w][rt * 16 + quad * 4 + rg][ct * 16 + l16] = 0;
        } else if (diag) {
#pragma unroll
          for (int rg = 0; rg < 4; ++rg) {
            int r16 = quad * 4 + rg;      // row within diag tile
            float p = exp2f(s[rt][ct][rg]);
            if (c == 0) p = (l16 < r16) ? 0.f : p;
            else        p = (l16 > r16) ? 0.f : p;
            pl[w][rt * 16 + r16][ct * 16 + l16] = f2bf_rtz(p);
          }
        } else {
#pragma unroll
          for (int rg = 0; rg < 4; ++rg)
            pl[w][rt * 16 + quad * 4 + rg][ct * 16 + l16] = f2bf_rtz(exp2f(s[rt][ct][rg]));
        }
      }
    }

    __syncthreads();   // order P-stores before cross-lane P-loads

    // O += P V ; row sums via ones-fragment; skip dead ks-tiles
#pragma unroll
    for (int ks = 0; ks < 4; ++ks) {
      bool anyrt = (c == 0) ? (2 * ks + 1 >= w * 2) : (c == 2) ? (2 * ks <= w * 2 + 1) : true;
      if (!anyrt) continue;
      short8 vf[4];
#pragma unroll
      for (int ct = 0; ct < 4; ++ct)
        vf[ct] = *(const short8*)(&vt[ct * 16 + l16][ks * 32 + quad * 8]);
#pragma unroll
      for (int rt = 0; rt < 2; ++rt) {
        int wrt = w * 2 + rt;
        bool ksDead = (c == 0) ? (2 * ks + 1 < wrt) : (c == 2) ? (2 * ks > wrt) : false;
        if (ksDead) continue;
        short8 pf = *(const short8*)(&pl[w][rt * 16 + l16][ks * 32 + quad * 8]);
#pragma unroll
        for (int ct = 0; ct < 4; ++ct) o[rt][ct] = MFMA_B16(pf, vf[ct], o[rt][ct]);
        osum[rt] = MFMA_B16(pf, onesf, osum[rt]);
      }
    }
  }

  // normalize + store to (B, L, C) bf16; sum lives in col 0 of the ones tile
#pragma unroll
  for (int rt = 0; rt < 2; ++rt) {
#pragma unroll
    for (int rg = 0; rg < 4; ++rg) {
      float ssum = __shfl(osum[rt][rg], lane & 48);
      float inv = 1.f / ssum;
      int r = n * 128 + w * 32 + rt * 16 + quad * 4 + rg;
#pragma unroll
      for (int ct = 0; ct < 4; ++ct)
        attnb[(size_t)(b * L + r) * 1024 + h * 64 + ct * 16 + l16] =
            f2bf(o[rt][ct][rg] * inv);
    }
  }
}

// ---------------- output projection GEMM (fp32 out), 128x128 ----------------
__global__ __launch_bounds__(256) void gemm_out(
    const short* __restrict__ attnb, const short* __restrict__ wTo,
    const float* __restrict__ bo, float* __restrict__ outp) {
  const int K = 1024;
  int m0 = blockIdx.x * 128, n0 = blockIdx.y * 128;
  __shared__ __align__(16) short a[128][32];
  __shared__ __align__(16) short bt[128][32];
  int tid = threadIdx.x;
  int w = tid >> 6, lane = tid & 63, quad = lane >> 4, l16 = lane & 15;
  int wm = (w >> 1) * 64, wn = (w & 1) * 64;
  floatx4 zf = {0.f, 0.f, 0.f, 0.f};
  floatx4 acc[4][4];
#pragma unroll
  for (int i = 0; i < 4; ++i)
#pragma unroll
    for (int j = 0; j < 4; ++j) acc[i][j] = zf;

  int rowL = lane >> 2;
  int segL = (lane & 3) * 8;
  const short* ga = attnb + (size_t)(m0 + w * 32 + rowL) * K + segL;
  const short* gb = wTo + (size_t)(n0 + w * 32 + rowL) * K + segL;
  short* la = &a[w * 32][0];
  short* lb = &bt[w * 32][0];

  for (int k0 = 0; k0 < K; k0 += 32) {
    __syncthreads();
    gload_lds16(ga + k0, la);
    gload_lds16(ga + (size_t)16 * K + k0, la + 16 * 32);
    gload_lds16(gb + k0, lb);
    gload_lds16(gb + (size_t)16 * K + k0, lb + 16 * 32);
    __syncthreads();
    short8 af[4], bf[4];
#pragma unroll
    for (int t = 0; t < 4; ++t) {
      af[t] = *(const short8*)(&a[wm + t * 16 + l16][quad * 8]);
      bf[t] = *(const short8*)(&bt[wn + t * 16 + l16][quad * 8]);
    }
#pragma unroll
    for (int i = 0; i < 4; ++i)
#pragma unroll
      for (int j = 0; j < 4; ++j)
        acc[i][j] = MFMA_B16(af[i], bf[j], acc[i][j]);
  }
#pragma unroll
  for (int i = 0; i < 4; ++i)
#pragma unroll
    for (int j = 0; j < 4; ++j)
#pragma unroll
      for (int rg = 0; rg < 4; ++rg) {
        int m = m0 + wm + i * 16 + quad * 4 + rg;
        int c = n0 + wn + j * 16 + l16;
        outp[(size_t)m * 1024 + c] = acc[i][j][rg] + bo[c];
      }
}

extern "C" void kernel_launch(void* const* d_in, const int* in_sizes, int n_in,
                              void* d_out, int out_size, void* d_ws, size_t ws_size,
                              hipStream_t stream) {
  const float* x  = (const float*)d_in[0];
  const float* wq = (const float*)d_in[1];
  const float* bq = (const float*)d_in[2];
  const float* wk = (const float*)d_in[3];
  const float* bk = (const float*)d_in[4];
  const float* wv = (const float*)d_in[5];
  const float* bv = (const float*)d_in[6];
  const float* wo = (const float*)d_in[7];
  const float* bo = (const float*)d_in[8];

  char* ws = (char*)d_ws;
  short* xb    = (short*)ws;                   // [0,16M): x bf16
  short* wT    = (short*)(ws + (16u << 20));   // [16M,24M): 4x W^T bf16
  short* qkv   = (short*)(ws + (24u << 20));   // [24M,72M): Q,K,V in (B,H,L,D)
  short* attnb = (short*)(ws + (72u << 20));   // [72M,88M): attention out (B,L,C) bf16

  prep<<<12288, 256, 0, stream>>>((const float4*)x, (short4v*)xb, wq, wk, wv, wo, wT);
  gemm_qkv<<<dim3(64, 8, 3), 256, 0, stream>>>(xb, wT, bq, bk, bv, qkv);
  attn_kern<<<dim3(32, 16, 2), 256, 0, stream>>>(qkv, attnb);
  gemm_out<<<dim3(64, 8), 256, 0, stream>>>(attnb, wT + 3u * 1024 * 1024, bo, (float*)d_out);
}